// Round 1
// baseline (226.932 us; speedup 1.0000x reference)
//
#include <hip/hip_runtime.h>
#include <stdint.h>

// FaceWeightedFusion: B=4, H=W=1024, N=262144, all inputs fp32.
// Binary-mask erosion collapsed to capped L-inf distance transform:
//   weight(p) = 0 (mask=0) | 1.0 (d>=46) | 0.1+0.06*floor((d-1)/3)
// ws layout: [0,4MB) row-DT u8, [4MB,8MB) weight-bucket u8. Needs ws_size >= 8MB.

#define HH 1024
#define WW 1024
#define HWIMG (HH * WW)
#define NPTS 262144

static __device__ __forceinline__ uint32_t umin_(uint32_t a, uint32_t b) { return a < b ? a : b; }
static __device__ __forceinline__ uint32_t umax_(uint32_t a, uint32_t b) { return a > b ? a : b; }

// ---------------- Kernel 1: row distance transform (capped 46) ----------------
// One wave per row. Ballot builds zero-bitmap: word i covers pixels [64i,64i+64).
__global__ __launch_bounds__(256) void row_dt_kernel(const float* __restrict__ mask,
                                                     uint8_t* __restrict__ rbuf) {
    __shared__ uint64_t words[4][18];
    const int w = threadIdx.x >> 6;
    const int l = threadIdx.x & 63;
    const int row = blockIdx.x * 4 + w;   // row in [0, 4096) = b*1024 + y
    const float* mrow = mask + (size_t)row * WW;

    if (l == 0) { words[w][0] = 0ull; words[w][17] = 0ull; }
    for (int i = 0; i < 16; ++i) {
        float m = mrow[i * 64 + l];
        uint64_t bm = __ballot(m == 0.0f);
        if (l == 0) words[w][i + 1] = bm;
    }
    __syncthreads();

    uint8_t* rrow = rbuf + (size_t)row * WW;
    for (int i = 0; i < 16; ++i) {
        uint64_t W0 = words[w][i];       // left word
        uint64_t W1 = words[w][i + 1];   // current word
        uint64_t W2 = words[w][i + 2];   // right word
        // bit j of rmask = zero at pixel x+j ; bit (63-j) of lmask = zero at pixel x-j
        uint64_t rmask = (W1 >> l) | ((W2 << 1) << (63 - l));
        uint64_t lmask = (W1 << (63 - l)) | ((W0 >> 1) >> l);
        int dr = rmask ? __builtin_ctzll(rmask) : 64;
        int dl = lmask ? __builtin_clzll(lmask) : 64;
        int d = dr < dl ? dr : dl;
        if (d > 46) d = 46;
        rrow[i * 64 + l] = (uint8_t)d;
    }
}

// ------------- Kernel 2: column pass -> D = min_dy max(|dy|, r(y+dy)) -------------
// Tile 64 cols x 64 rows. LDS column-major u8, stride 156 (39 words, odd -> no bank conflicts).
#define K2_STRIDE 156
__global__ __launch_bounds__(256) void col_dt_kernel(const uint8_t* __restrict__ rbuf,
                                                     uint8_t* __restrict__ wbuf) {
    __shared__ uint8_t lds[64 * K2_STRIDE];
    const int bx = blockIdx.x;
    const int tx = bx & 15, ty = (bx >> 4) & 15, b = bx >> 8;
    const int x0 = tx * 64, y0 = ty * 64;
    const int c = threadIdx.x & 63;   // column within tile (lane)
    const int t = threadIdx.x >> 6;   // wave id, uniform within wave

    const uint8_t* img = rbuf + (size_t)b * HWIMG;
    // Stage rows [y0-45, y0+108] (154 rows). Outside image => 46 (no zeros beyond border).
    for (int rr = t; rr < 154; rr += 4) {
        int gy = y0 - 45 + rr;
        uint8_t v = 46;
        if (gy >= 0 && gy < HH) v = img[(size_t)gy * WW + x0 + c];
        lds[c * K2_STRIDE + rr] = v;
    }
    __syncthreads();

    const uint8_t* col = lds + c * K2_STRIDE;
    uint8_t* outp = wbuf + (size_t)b * HWIMG;
    for (int j = 0; j < 16; ++j) {
        const int yl = t + 4 * j;          // row within tile
        const int a0 = yl & ~3;            // aligned window start (wave-uniform)
        uint32_t D = 46;
        int dy = a0 - yl - 45;             // dy of first byte, wave-uniform -> scalar pipe
#pragma unroll
        for (int k = 0; k < 24; ++k) {
            uint32_t v = *(const uint32_t*)(col + a0 + 4 * k);
            // bytes beyond the true window have |dy|>=46 -> max() >= 46 -> harmless
            uint32_t A0 = (uint32_t)abs(dy);
            uint32_t A1 = (uint32_t)abs(dy + 1);
            uint32_t A2 = (uint32_t)abs(dy + 2);
            uint32_t A3 = (uint32_t)abs(dy + 3);
            uint32_t m0 = umax_(A0, v & 0xffu);
            uint32_t m1 = umax_(A1, (v >> 8) & 0xffu);
            uint32_t m2 = umax_(A2, (v >> 16) & 0xffu);
            uint32_t m3 = umax_(A3, v >> 24);
            D = umin_(D, umin_(umin_(m0, m1), umin_(m2, m3)));
            dy += 4;
        }
        // bucket: 255 = mask==0 (weight 0); 15 = survivor (1.0); else i = (D-1)/3
        uint8_t o = (D == 0) ? (uint8_t)255 : (uint8_t)umin_(15u, (D - 1u) / 3u);
        outp[(size_t)(y0 + yl) * WW + x0 + c] = o;
    }
}

// ---------------- Kernel 3: bilinear sampling + fusion ----------------
static __device__ __forceinline__ float decode_w(uint8_t k) {
    if (k == 255) return 0.0f;
    float v = 0.1f + (float)k * 0.06f;
    return v < 1.0f ? v : 1.0f;
}

__global__ __launch_bounds__(256) void sample_kernel(
    const float* __restrict__ edge_img, const float* __restrict__ depth_img,
    const uint8_t* __restrict__ wimg, const float* __restrict__ xy,
    const float* __restrict__ z, const float* __restrict__ occ_body,
    const float* __restrict__ occ_face, float* __restrict__ out) {
    const int tid = blockIdx.x * 256 + threadIdx.x;
    const int b = tid >> 18;
    const int n = tid & (NPTS - 1);

    float x = xy[(size_t)b * 2 * NPTS + n];
    float y = xy[(size_t)b * 2 * NPTS + NPTS + n];
    // (x+1)*0.5 is exact (mul by 0.5); then one rounding at *1023 — matches np order.
    float fx = ((x + 1.0f) * 0.5f) * 1023.0f;
    float fy = ((y + 1.0f) * 0.5f) * 1023.0f;
    float x0f = floorf(fx), y0f = floorf(fy);
    float wx = fx - x0f, wy = fy - y0f;
    int x0i = (int)x0f; x0i = x0i < 0 ? 0 : (x0i > 1023 ? 1023 : x0i);
    int y0i = (int)y0f; y0i = y0i < 0 ? 0 : (y0i > 1023 ? 1023 : y0i);
    int x1i = x0i + 1 > 1023 ? 1023 : x0i + 1;
    int y1i = y0i + 1 > 1023 ? 1023 : y0i + 1;

    const size_t base = (size_t)b * HWIMG;
    const size_t i00 = base + (size_t)y0i * WW + x0i;
    const size_t i01 = base + (size_t)y0i * WW + x1i;
    const size_t i10 = base + (size_t)y1i * WW + x0i;
    const size_t i11 = base + (size_t)y1i * WW + x1i;

    const float w00 = (1.0f - wx) * (1.0f - wy);
    const float w01 = wx * (1.0f - wy);
    const float w10 = (1.0f - wx) * wy;
    const float w11 = wx * wy;

    float e = edge_img[i00] * w00 + edge_img[i01] * w01
            + edge_img[i10] * w10 + edge_img[i11] * w11;

    float zv = z[(size_t)b * NPTS + n];
    float ob = occ_body[(size_t)b * NPTS + n];
    float of = occ_face[(size_t)b * NPTS + n];

    float w = 0.0f;
    if (e > 0.01f) {
        float dq = depth_img[i00] * w00 + depth_img[i01] * w01
                 + depth_img[i10] * w10 + depth_img[i11] * w11;
        float la = decode_w(wimg[i00]) * w00 + decode_w(wimg[i01]) * w01
                 + decode_w(wimg[i10]) * w10 + decode_w(wimg[i11]) * w11;
        float ps = zv - dq;
        w = expf(-(ps * ps) * 1000.0f) * la;
    }
    out[(size_t)b * NPTS + n] = w * of + (1.0f - w) * ob;
}

extern "C" void kernel_launch(void* const* d_in, const int* in_sizes, int n_in,
                              void* d_out, int out_size, void* d_ws, size_t ws_size,
                              hipStream_t stream) {
    const float* mask      = (const float*)d_in[0];
    const float* depth     = (const float*)d_in[1];
    const float* edge      = (const float*)d_in[2];
    const float* xy        = (const float*)d_in[3];
    const float* z         = (const float*)d_in[4];
    const float* occ_body  = (const float*)d_in[5];
    const float* occ_face  = (const float*)d_in[6];
    float* out = (float*)d_out;

    uint8_t* rbuf = (uint8_t*)d_ws;              // 4 MB
    uint8_t* wbuf = rbuf + (size_t)4 * HWIMG;    // 4 MB

    row_dt_kernel<<<1024, 256, 0, stream>>>(mask, rbuf);
    col_dt_kernel<<<1024, 256, 0, stream>>>(rbuf, wbuf);
    sample_kernel<<<4096, 256, 0, stream>>>(edge, depth, wbuf, xy, z,
                                            occ_body, occ_face, out);
}

// Round 2
// 180.939 us; speedup vs baseline: 1.2542x; 1.2542x over previous
//
#include <hip/hip_runtime.h>
#include <stdint.h>

// FaceWeightedFusion: B=4, H=W=1024, N=262144, all fp32 in/out.
// Erosion collapsed to capped L-inf distance transform (binary mask):
//   weight(p) = 0 (mask=0) | table[min(15,(d-1)/3)], table[k]=0.1+0.06k (k=15 -> ~1.0)
// Pass 1: row DT (ballot bitmap + ctz/clz), u8, cap 46.
// Pass 2: column min-max envelope D = min_dy max(|dy|, r(y+dy)) via v_pk_{max,min}_i16
//         on a register-resident window (no LDS); fused write of packed 8B/px image
//         {depth f32 bits, edge(0/1) u16 | bucket u16<<16}.
// Pass 3: 4x dwordx2 bilinear gathers + exp + lerp.
// ws: [0,4MB) rbuf u8; packed path: [4MB,36MB) packed image. Fallback (<36MB ws):
//     [4MB,8MB) bucket u8, sample reads 3 separate images.

#define HH 1024
#define WW 1024
#define HWIMG (HH * WW)
#define NPTS 262144

typedef short short2v __attribute__((ext_vector_type(2)));

static __device__ __forceinline__ uint32_t umin_(uint32_t a, uint32_t b) { return a < b ? a : b; }

// ---------------- Kernel 1: row distance transform (capped 46) ----------------
__global__ __launch_bounds__(256) void row_dt_kernel(const float* __restrict__ mask,
                                                     uint8_t* __restrict__ rbuf) {
    __shared__ uint64_t words[4][18];
    const int w = threadIdx.x >> 6;
    const int l = threadIdx.x & 63;
    const int row = blockIdx.x * 4 + w;   // b*1024 + y
    const float* mrow = mask + (size_t)row * WW;

    if (l == 0) { words[w][0] = 0ull; words[w][17] = 0ull; }
    for (int i = 0; i < 16; ++i) {
        float m = mrow[i * 64 + l];
        uint64_t bm = __ballot(m == 0.0f);
        if (l == 0) words[w][i + 1] = bm;
    }
    __syncthreads();

    uint8_t* rrow = rbuf + (size_t)row * WW;
    for (int i = 0; i < 16; ++i) {
        uint64_t W0 = words[w][i];
        uint64_t W1 = words[w][i + 1];
        uint64_t W2 = words[w][i + 2];
        uint64_t rmask = (W1 >> l) | ((W2 << 1) << (63 - l));
        uint64_t lmask = (W1 << (63 - l)) | ((W0 >> 1) >> l);
        int dr = rmask ? __builtin_ctzll(rmask) : 64;
        int dl = lmask ? __builtin_clzll(lmask) : 64;
        int d = dr < dl ? dr : dl;
        if (d > 46) d = 46;
        rrow[i * 64 + l] = (uint8_t)d;
    }
}

// ------------- Kernel 2: column pass, packed-i16, register window -------------
// Thread = one column (lane) x 16 consecutive rows. Window rows [ybase-46, ybase+61]
// held as 54 u32 = (r_even, r_odd) i16 pairs. Per pixel i: 47 pk_max + 47 pk_min,
// A-pair constants fully static (both loops unrolled). Out-of-window elems have
// |dy|>=46 -> max>=cap -> harmless.
template<bool PACK>
__global__ __launch_bounds__(256) void col_dt_kernel(const uint8_t* __restrict__ rbuf,
                                                     const float* __restrict__ edge,
                                                     const float* __restrict__ depth,
                                                     uint8_t* __restrict__ bucket_out,
                                                     uint2* __restrict__ packed_out) {
    const int bx = blockIdx.x;
    const int tx = bx & 15, ty = (bx >> 4) & 15, b = bx >> 8;
    const int x0 = tx * 64, y0 = ty * 64;
    const int c = threadIdx.x & 63;
    const int t = threadIdx.x >> 6;
    const int ybase = y0 + t * 16;
    const uint8_t* img = rbuf + (size_t)b * HWIMG + x0 + c;

    uint32_t win[54];
#pragma unroll
    for (int j = 0; j < 54; ++j) {
        int r0 = ybase - 46 + 2 * j;
        int r1 = r0 + 1;
        int r0c = r0 < 0 ? 0 : (r0 > 1023 ? 1023 : r0);
        int r1c = r1 < 0 ? 0 : (r1 > 1023 ? 1023 : r1);
        uint32_t lo = img[(size_t)r0c * WW];            // coalesced 64B wave load
        uint32_t hi = img[(size_t)r1c * WW];
        if (r0 != r0c) lo = 46;
        if (r1 != r1c) hi = 46;
        win[j] = lo | (hi << 16);
    }

#pragma unroll
    for (int i = 0; i < 16; ++i) {
        const int base = i >> 1;
        const int par = i & 1;
        short2v D2 = (short2v){46, 46};
#pragma unroll
        for (int q = 0; q < 47; ++q) {
            int dy0 = 2 * q - 46 - par;                 // compile-time
            short a0 = (short)(dy0 < 0 ? -dy0 : dy0);
            short a1 = (short)(dy0 + 1 < 0 ? -(dy0 + 1) : dy0 + 1);
            short2v A = (short2v){a0, a1};
            short2v v = __builtin_bit_cast(short2v, win[base + q]);
            short2v mx = __builtin_elementwise_max(A, v);   // v_pk_max_i16
            D2 = __builtin_elementwise_min(D2, mx);         // v_pk_min_i16
        }
        uint32_t D = (uint32_t)(D2.x < D2.y ? D2.x : D2.y);
        uint8_t o = (D == 0) ? (uint8_t)255 : (uint8_t)umin_(15u, (D - 1u) / 3u);
        const size_t pix = (size_t)b * HWIMG + (size_t)(ybase + i) * WW + x0 + c;
        if (PACK) {
            float dv = depth[pix];
            float ev = edge[pix];                       // exactly 0.0f or 1.0f
            uint32_t w1 = (ev != 0.0f ? 1u : 0u) | ((uint32_t)o << 16);
            packed_out[pix] = make_uint2(__builtin_bit_cast(uint32_t, dv), w1);
        } else {
            bucket_out[pix] = o;
        }
    }
}

// ---------------- Kernel 3: bilinear sampling + fusion ----------------
static __device__ __forceinline__ float decode_w(uint32_t k) {
    if (k == 255u) return 0.0f;
    float v = 0.1f + (float)k * 0.06f;
    return v < 1.0f ? v : 1.0f;
}

template<bool PACKED>
__global__ __launch_bounds__(256) void sample_kernel(
    const uint2* __restrict__ pimg,
    const float* __restrict__ edge_img, const float* __restrict__ depth_img,
    const uint8_t* __restrict__ wimg,
    const float* __restrict__ xy, const float* __restrict__ z,
    const float* __restrict__ occ_body, const float* __restrict__ occ_face,
    float* __restrict__ out) {
    const int tid = blockIdx.x * 256 + threadIdx.x;
    const int b = tid >> 18;
    const int n = tid & (NPTS - 1);

    float x = xy[(size_t)b * 2 * NPTS + n];
    float y = xy[(size_t)b * 2 * NPTS + NPTS + n];
    float fx = ((x + 1.0f) * 0.5f) * 1023.0f;
    float fy = ((y + 1.0f) * 0.5f) * 1023.0f;
    float x0f = floorf(fx), y0f = floorf(fy);
    float wx = fx - x0f, wy = fy - y0f;
    int x0i = (int)x0f; x0i = x0i < 0 ? 0 : (x0i > 1023 ? 1023 : x0i);
    int y0i = (int)y0f; y0i = y0i < 0 ? 0 : (y0i > 1023 ? 1023 : y0i);
    int x1i = x0i + 1 > 1023 ? 1023 : x0i + 1;
    int y1i = y0i + 1 > 1023 ? 1023 : y0i + 1;

    const size_t base = (size_t)b * HWIMG;
    const size_t i00 = base + (size_t)y0i * WW + x0i;
    const size_t i01 = base + (size_t)y0i * WW + x1i;
    const size_t i10 = base + (size_t)y1i * WW + x0i;
    const size_t i11 = base + (size_t)y1i * WW + x1i;

    const float w00 = (1.0f - wx) * (1.0f - wy);
    const float w01 = wx * (1.0f - wy);
    const float w10 = (1.0f - wx) * wy;
    const float w11 = wx * wy;

    float zv = z[(size_t)b * NPTS + n];
    float ob = occ_body[(size_t)b * NPTS + n];
    float of = occ_face[(size_t)b * NPTS + n];

    float w = 0.0f;
    if (PACKED) {
        uint2 p00 = pimg[i00], p01 = pimg[i01], p10 = pimg[i10], p11 = pimg[i11];
        float e = (float)(p00.y & 0xffffu) * w00 + (float)(p01.y & 0xffffu) * w01
                + (float)(p10.y & 0xffffu) * w10 + (float)(p11.y & 0xffffu) * w11;
        if (e > 0.01f) {
            float dq = __builtin_bit_cast(float, p00.x) * w00
                     + __builtin_bit_cast(float, p01.x) * w01
                     + __builtin_bit_cast(float, p10.x) * w10
                     + __builtin_bit_cast(float, p11.x) * w11;
            float la = decode_w(p00.y >> 16) * w00 + decode_w(p01.y >> 16) * w01
                     + decode_w(p10.y >> 16) * w10 + decode_w(p11.y >> 16) * w11;
            float ps = zv - dq;
            w = expf(-(ps * ps) * 1000.0f) * la;
        }
    } else {
        float e = edge_img[i00] * w00 + edge_img[i01] * w01
                + edge_img[i10] * w10 + edge_img[i11] * w11;
        if (e > 0.01f) {
            float dq = depth_img[i00] * w00 + depth_img[i01] * w01
                     + depth_img[i10] * w10 + depth_img[i11] * w11;
            float la = decode_w(wimg[i00]) * w00 + decode_w(wimg[i01]) * w01
                     + decode_w(wimg[i10]) * w10 + decode_w(wimg[i11]) * w11;
            float ps = zv - dq;
            w = expf(-(ps * ps) * 1000.0f) * la;
        }
    }
    out[(size_t)b * NPTS + n] = w * of + (1.0f - w) * ob;
}

extern "C" void kernel_launch(void* const* d_in, const int* in_sizes, int n_in,
                              void* d_out, int out_size, void* d_ws, size_t ws_size,
                              hipStream_t stream) {
    const float* mask      = (const float*)d_in[0];
    const float* depth     = (const float*)d_in[1];
    const float* edge      = (const float*)d_in[2];
    const float* xy        = (const float*)d_in[3];
    const float* z         = (const float*)d_in[4];
    const float* occ_body  = (const float*)d_in[5];
    const float* occ_face  = (const float*)d_in[6];
    float* out = (float*)d_out;

    uint8_t* rbuf = (uint8_t*)d_ws;                          // 4 MB
    const size_t need_packed = (size_t)4 * HWIMG + (size_t)4 * HWIMG * 8;  // 36 MB

    row_dt_kernel<<<1024, 256, 0, stream>>>(mask, rbuf);

    if (ws_size >= need_packed) {
        uint2* pimg = (uint2*)(rbuf + (size_t)4 * HWIMG);    // 32 MB
        col_dt_kernel<true><<<1024, 256, 0, stream>>>(rbuf, edge, depth, nullptr, pimg);
        sample_kernel<true><<<4096, 256, 0, stream>>>(pimg, nullptr, nullptr, nullptr,
                                                      xy, z, occ_body, occ_face, out);
    } else {
        uint8_t* wbuf = rbuf + (size_t)4 * HWIMG;            // 4 MB
        col_dt_kernel<false><<<1024, 256, 0, stream>>>(rbuf, edge, depth, wbuf, nullptr);
        sample_kernel<false><<<4096, 256, 0, stream>>>(nullptr, edge, depth, wbuf,
                                                       xy, z, occ_body, occ_face, out);
    }
}

// Round 3
// 152.423 us; speedup vs baseline: 1.4888x; 1.1871x over previous
//
#include <hip/hip_runtime.h>
#include <stdint.h>

// FaceWeightedFusion: B=4, H=W=1024, N=262144, all fp32 in/out.
// Erosion collapsed to capped L-inf distance transform (binary mask):
//   weight(p) = 0 (mask=0) | table[min(15,(d-1)/3)], table[k]=0.1+0.06k (k=15 -> 1.0)
// Pass 1: row DT (ballot bitmap + ctz/clz), u8, cap 46.
// Pass 2: column envelope D = min_dy max(|dy|, r(y+dy)) via v_pk_{max,min}_i16 on a
//         register window; fused 4B/px packed write:
//         bits[0:19] depth*1048575 fixed  [20:24] bucket (31=mask0)  [25] edge bit.
//         Per-batch packed image = 4 MB = one XCD L2.
// Pass 3: sample with XCD-affinity swizzle (blockIdx%4 == batch) so each XCD's
//         gathers stay inside its own 4 MB L2; nt hints on all streaming traffic.
// ws: [0,4MB) rbuf u8, [4MB,20MB) packed u32. Fallback (<20MB ws): u8 bucket path.

#define HH 1024
#define WW 1024
#define HWIMG (HH * WW)
#define NPTS 262144

typedef short short2v __attribute__((ext_vector_type(2)));

static __device__ __forceinline__ uint32_t umin_(uint32_t a, uint32_t b) { return a < b ? a : b; }

// ---------------- Kernel 1: row distance transform (capped 46) ----------------
__global__ __launch_bounds__(256) void row_dt_kernel(const float* __restrict__ mask,
                                                     uint8_t* __restrict__ rbuf) {
    __shared__ uint64_t words[4][18];
    const int w = threadIdx.x >> 6;
    const int l = threadIdx.x & 63;
    const int row = blockIdx.x * 4 + w;   // b*1024 + y
    const float* mrow = mask + (size_t)row * WW;

    if (l == 0) { words[w][0] = 0ull; words[w][17] = 0ull; }
    for (int i = 0; i < 16; ++i) {
        float m = __builtin_nontemporal_load(&mrow[i * 64 + l]);
        uint64_t bm = __ballot(m == 0.0f);
        if (l == 0) words[w][i + 1] = bm;
    }
    __syncthreads();

    uint8_t* rrow = rbuf + (size_t)row * WW;
    for (int i = 0; i < 16; ++i) {
        uint64_t W0 = words[w][i];
        uint64_t W1 = words[w][i + 1];
        uint64_t W2 = words[w][i + 2];
        uint64_t rmask = (W1 >> l) | ((W2 << 1) << (63 - l));
        uint64_t lmask = (W1 << (63 - l)) | ((W0 >> 1) >> l);
        int dr = rmask ? __builtin_ctzll(rmask) : 64;
        int dl = lmask ? __builtin_clzll(lmask) : 64;
        int d = dr < dl ? dr : dl;
        if (d > 46) d = 46;
        rrow[i * 64 + l] = (uint8_t)d;
    }
}

// ------------- Kernel 2: column pass, packed-i16, register window -------------
template<bool PACK>
__global__ __launch_bounds__(256) void col_dt_kernel(const uint8_t* __restrict__ rbuf,
                                                     const float* __restrict__ edge,
                                                     const float* __restrict__ depth,
                                                     uint8_t* __restrict__ bucket_out,
                                                     uint32_t* __restrict__ packed_out) {
    const int bx = blockIdx.x;
    const int tx = bx & 15, ty = (bx >> 4) & 15, b = bx >> 8;
    const int x0 = tx * 64, y0 = ty * 64;
    const int c = threadIdx.x & 63;
    const int t = threadIdx.x >> 6;
    const int ybase = y0 + t * 16;
    const uint8_t* img = rbuf + (size_t)b * HWIMG + x0 + c;

    uint32_t win[54];
#pragma unroll
    for (int j = 0; j < 54; ++j) {
        int r0 = ybase - 46 + 2 * j;
        int r1 = r0 + 1;
        int r0c = r0 < 0 ? 0 : (r0 > 1023 ? 1023 : r0);
        int r1c = r1 < 0 ? 0 : (r1 > 1023 ? 1023 : r1);
        uint32_t lo = img[(size_t)r0c * WW];            // coalesced 64B wave load
        uint32_t hi = img[(size_t)r1c * WW];
        if (r0 != r0c) lo = 46;
        if (r1 != r1c) hi = 46;
        win[j] = lo | (hi << 16);
    }

#pragma unroll
    for (int i = 0; i < 16; ++i) {
        const int base = i >> 1;
        const int par = i & 1;
        short2v D2 = (short2v){46, 46};
#pragma unroll
        for (int q = 0; q < 47; ++q) {
            int dy0 = 2 * q - 46 - par;                 // compile-time
            short a0 = (short)(dy0 < 0 ? -dy0 : dy0);
            short a1 = (short)(dy0 + 1 < 0 ? -(dy0 + 1) : dy0 + 1);
            short2v A = (short2v){a0, a1};
            short2v v = __builtin_bit_cast(short2v, win[base + q]);
            short2v mx = __builtin_elementwise_max(A, v);   // v_pk_max_i16
            D2 = __builtin_elementwise_min(D2, mx);         // v_pk_min_i16
        }
        uint32_t D = (uint32_t)(D2.x < D2.y ? D2.x : D2.y);
        const size_t pix = (size_t)b * HWIMG + (size_t)(ybase + i) * WW + x0 + c;
        if (PACK) {
            float dv = __builtin_nontemporal_load(&depth[pix]);
            float ev = __builtin_nontemporal_load(&edge[pix]);   // exactly 0.0f/1.0f
            uint32_t q20 = (uint32_t)fminf(rintf(dv * 1048575.0f), 1048575.0f);
            uint32_t bk = (D == 0) ? 31u : umin_(15u, (D - 1u) / 3u);
            uint32_t word = q20 | (bk << 20) | ((ev != 0.0f ? 1u : 0u) << 25);
            __builtin_nontemporal_store(word, &packed_out[pix]);
        } else {
            uint8_t o = (D == 0) ? (uint8_t)255 : (uint8_t)umin_(15u, (D - 1u) / 3u);
            bucket_out[pix] = o;
        }
    }
}

// ---------------- Kernel 3: bilinear sampling + fusion ----------------
static __device__ __forceinline__ float decode_w8(uint32_t k) {  // u8 bucket
    if (k == 255u) return 0.0f;
    float v = 0.1f + (float)k * 0.06f;
    return v < 1.0f ? v : 1.0f;
}
static __device__ __forceinline__ float decode_w5(uint32_t p) {  // packed bucket
    uint32_t k = (p >> 20) & 31u;
    if (k == 31u) return 0.0f;
    float v = 0.1f + (float)k * 0.06f;
    return v < 1.0f ? v : 1.0f;
}

template<bool PACKED>
__global__ __launch_bounds__(256) void sample_kernel(
    const uint32_t* __restrict__ pimg,
    const float* __restrict__ edge_img, const float* __restrict__ depth_img,
    const uint8_t* __restrict__ wimg,
    const float* __restrict__ xy, const float* __restrict__ z,
    const float* __restrict__ occ_body, const float* __restrict__ occ_face,
    float* __restrict__ out) {
    // XCD-affinity: batch = blockIdx%4 -> under round-robin block->XCD dispatch,
    // XCD x only gathers from image (x&3), a 4 MB working set = its own L2.
    const int b = blockIdx.x & 3;
    const int n = (blockIdx.x >> 2) * 256 + threadIdx.x;

    float x = __builtin_nontemporal_load(&xy[(size_t)b * 2 * NPTS + n]);
    float y = __builtin_nontemporal_load(&xy[(size_t)b * 2 * NPTS + NPTS + n]);
    float fx = ((x + 1.0f) * 0.5f) * 1023.0f;
    float fy = ((y + 1.0f) * 0.5f) * 1023.0f;
    float x0f = floorf(fx), y0f = floorf(fy);
    float wx = fx - x0f, wy = fy - y0f;
    int x0i = (int)x0f; x0i = x0i < 0 ? 0 : (x0i > 1023 ? 1023 : x0i);
    int y0i = (int)y0f; y0i = y0i < 0 ? 0 : (y0i > 1023 ? 1023 : y0i);
    int x1i = x0i + 1 > 1023 ? 1023 : x0i + 1;
    int y1i = y0i + 1 > 1023 ? 1023 : y0i + 1;

    const size_t base = (size_t)b * HWIMG;
    const size_t i00 = base + (size_t)y0i * WW + x0i;
    const size_t i01 = base + (size_t)y0i * WW + x1i;
    const size_t i10 = base + (size_t)y1i * WW + x0i;
    const size_t i11 = base + (size_t)y1i * WW + x1i;

    const float w00 = (1.0f - wx) * (1.0f - wy);
    const float w01 = wx * (1.0f - wy);
    const float w10 = (1.0f - wx) * wy;
    const float w11 = wx * wy;

    float zv = __builtin_nontemporal_load(&z[(size_t)b * NPTS + n]);
    float ob = __builtin_nontemporal_load(&occ_body[(size_t)b * NPTS + n]);
    float of = __builtin_nontemporal_load(&occ_face[(size_t)b * NPTS + n]);

    float w = 0.0f;
    if (PACKED) {
        uint32_t p00 = pimg[i00], p01 = pimg[i01], p10 = pimg[i10], p11 = pimg[i11];
        float e = (float)((p00 >> 25) & 1u) * w00 + (float)((p01 >> 25) & 1u) * w01
                + (float)((p10 >> 25) & 1u) * w10 + (float)((p11 >> 25) & 1u) * w11;
        if (e > 0.01f) {
            const float DQS = 1.0f / 1048575.0f;
            float dq = ((float)(p00 & 0xFFFFFu) * w00 + (float)(p01 & 0xFFFFFu) * w01
                      + (float)(p10 & 0xFFFFFu) * w10 + (float)(p11 & 0xFFFFFu) * w11) * DQS;
            float la = decode_w5(p00) * w00 + decode_w5(p01) * w01
                     + decode_w5(p10) * w10 + decode_w5(p11) * w11;
            float ps = zv - dq;
            w = expf(-(ps * ps) * 1000.0f) * la;
        }
    } else {
        float e = edge_img[i00] * w00 + edge_img[i01] * w01
                + edge_img[i10] * w10 + edge_img[i11] * w11;
        if (e > 0.01f) {
            float dq = depth_img[i00] * w00 + depth_img[i01] * w01
                     + depth_img[i10] * w10 + depth_img[i11] * w11;
            float la = decode_w8(wimg[i00]) * w00 + decode_w8(wimg[i01]) * w01
                     + decode_w8(wimg[i10]) * w10 + decode_w8(wimg[i11]) * w11;
            float ps = zv - dq;
            w = expf(-(ps * ps) * 1000.0f) * la;
        }
    }
    __builtin_nontemporal_store(w * of + (1.0f - w) * ob, &out[(size_t)b * NPTS + n]);
}

extern "C" void kernel_launch(void* const* d_in, const int* in_sizes, int n_in,
                              void* d_out, int out_size, void* d_ws, size_t ws_size,
                              hipStream_t stream) {
    const float* mask      = (const float*)d_in[0];
    const float* depth     = (const float*)d_in[1];
    const float* edge      = (const float*)d_in[2];
    const float* xy        = (const float*)d_in[3];
    const float* z         = (const float*)d_in[4];
    const float* occ_body  = (const float*)d_in[5];
    const float* occ_face  = (const float*)d_in[6];
    float* out = (float*)d_out;

    uint8_t* rbuf = (uint8_t*)d_ws;                          // 4 MB
    const size_t need_packed = (size_t)4 * HWIMG + (size_t)4 * HWIMG * 4;  // 20 MB

    row_dt_kernel<<<1024, 256, 0, stream>>>(mask, rbuf);

    if (ws_size >= need_packed) {
        uint32_t* pimg = (uint32_t*)(rbuf + (size_t)4 * HWIMG);  // 16 MB
        col_dt_kernel<true><<<1024, 256, 0, stream>>>(rbuf, edge, depth, nullptr, pimg);
        sample_kernel<true><<<4096, 256, 0, stream>>>(pimg, nullptr, nullptr, nullptr,
                                                      xy, z, occ_body, occ_face, out);
    } else {
        uint8_t* wbuf = rbuf + (size_t)4 * HWIMG;            // 4 MB
        col_dt_kernel<false><<<1024, 256, 0, stream>>>(rbuf, edge, depth, wbuf, nullptr);
        sample_kernel<false><<<4096, 256, 0, stream>>>(nullptr, edge, depth, wbuf,
                                                       xy, z, occ_body, occ_face, out);
    }
}

// Round 4
// 150.917 us; speedup vs baseline: 1.5037x; 1.0100x over previous
//
#include <hip/hip_runtime.h>
#include <stdint.h>

// FaceWeightedFusion: B=4, H=W=1024, N=262144, all fp32 in/out.
// Erosion collapsed to capped L-inf distance transform (binary mask):
//   weight(p) = 0 (mask=0) | table[min(15,(d-1)/3)], table[k]=0.1+0.06k (k=15 -> 1.0)
// Pass 1: row DT (ballot bitmap + ctz/clz), u8, cap 46.
// Pass 2: column envelope D = min_dy max(|dy|, r(y+dy)) via v_pk_{max,min}_i16 on a
//         register window; fused 4B/px packed write:
//         bits[0:19] depth*1048575 fixed  [20:24] bucket (31=mask0)  [25] edge bit.
//         Per-batch packed image = 4 MB = one XCD L2.
// Pass 3: sample, 4 points/thread (16 gathers in flight -> latency hiding),
//         XCD-affinity swizzle (blockIdx%4 == batch), dwordx4 streams, nt hints.
// ws: [0,4MB) rbuf u8, [4MB,20MB) packed u32. Fallback (<20MB ws): u8 bucket path.

#define HH 1024
#define WW 1024
#define HWIMG (HH * WW)
#define NPTS 262144

typedef short short2v __attribute__((ext_vector_type(2)));
typedef float f32x4 __attribute__((ext_vector_type(4)));

static __device__ __forceinline__ uint32_t umin_(uint32_t a, uint32_t b) { return a < b ? a : b; }

// ---------------- Kernel 1: row distance transform (capped 46) ----------------
__global__ __launch_bounds__(256) void row_dt_kernel(const float* __restrict__ mask,
                                                     uint8_t* __restrict__ rbuf) {
    __shared__ uint64_t words[4][18];
    const int w = threadIdx.x >> 6;
    const int l = threadIdx.x & 63;
    const int row = blockIdx.x * 4 + w;   // b*1024 + y
    const float* mrow = mask + (size_t)row * WW;

    if (l == 0) { words[w][0] = 0ull; words[w][17] = 0ull; }
    for (int i = 0; i < 16; ++i) {
        float m = __builtin_nontemporal_load(&mrow[i * 64 + l]);
        uint64_t bm = __ballot(m == 0.0f);
        if (l == 0) words[w][i + 1] = bm;
    }
    __syncthreads();

    uint8_t* rrow = rbuf + (size_t)row * WW;
    for (int i = 0; i < 16; ++i) {
        uint64_t W0 = words[w][i];
        uint64_t W1 = words[w][i + 1];
        uint64_t W2 = words[w][i + 2];
        uint64_t rmask = (W1 >> l) | ((W2 << 1) << (63 - l));
        uint64_t lmask = (W1 << (63 - l)) | ((W0 >> 1) >> l);
        int dr = rmask ? __builtin_ctzll(rmask) : 64;
        int dl = lmask ? __builtin_clzll(lmask) : 64;
        int d = dr < dl ? dr : dl;
        if (d > 46) d = 46;
        rrow[i * 64 + l] = (uint8_t)d;
    }
}

// ------------- Kernel 2: column pass, packed-i16, register window -------------
template<bool PACK>
__global__ __launch_bounds__(256) void col_dt_kernel(const uint8_t* __restrict__ rbuf,
                                                     const float* __restrict__ edge,
                                                     const float* __restrict__ depth,
                                                     uint8_t* __restrict__ bucket_out,
                                                     uint32_t* __restrict__ packed_out) {
    const int bx = blockIdx.x;
    const int tx = bx & 15, ty = (bx >> 4) & 15, b = bx >> 8;
    const int x0 = tx * 64, y0 = ty * 64;
    const int c = threadIdx.x & 63;
    const int t = threadIdx.x >> 6;
    const int ybase = y0 + t * 16;
    const uint8_t* img = rbuf + (size_t)b * HWIMG + x0 + c;

    uint32_t win[54];
#pragma unroll
    for (int j = 0; j < 54; ++j) {
        int r0 = ybase - 46 + 2 * j;
        int r1 = r0 + 1;
        int r0c = r0 < 0 ? 0 : (r0 > 1023 ? 1023 : r0);
        int r1c = r1 < 0 ? 0 : (r1 > 1023 ? 1023 : r1);
        uint32_t lo = img[(size_t)r0c * WW];            // coalesced 64B wave load
        uint32_t hi = img[(size_t)r1c * WW];
        if (r0 != r0c) lo = 46;
        if (r1 != r1c) hi = 46;
        win[j] = lo | (hi << 16);
    }

#pragma unroll
    for (int i = 0; i < 16; ++i) {
        const int base = i >> 1;
        const int par = i & 1;
        short2v D2 = (short2v){46, 46};
#pragma unroll
        for (int q = 0; q < 47; ++q) {
            int dy0 = 2 * q - 46 - par;                 // compile-time
            short a0 = (short)(dy0 < 0 ? -dy0 : dy0);
            short a1 = (short)(dy0 + 1 < 0 ? -(dy0 + 1) : dy0 + 1);
            short2v A = (short2v){a0, a1};
            short2v v = __builtin_bit_cast(short2v, win[base + q]);
            short2v mx = __builtin_elementwise_max(A, v);   // v_pk_max_i16
            D2 = __builtin_elementwise_min(D2, mx);         // v_pk_min_i16
        }
        uint32_t D = (uint32_t)(D2.x < D2.y ? D2.x : D2.y);
        const size_t pix = (size_t)b * HWIMG + (size_t)(ybase + i) * WW + x0 + c;
        if (PACK) {
            float dv = __builtin_nontemporal_load(&depth[pix]);
            float ev = __builtin_nontemporal_load(&edge[pix]);   // exactly 0.0f/1.0f
            uint32_t q20 = (uint32_t)fminf(rintf(dv * 1048575.0f), 1048575.0f);
            uint32_t bk = (D == 0) ? 31u : umin_(15u, (D - 1u) / 3u);
            uint32_t word = q20 | (bk << 20) | ((ev != 0.0f ? 1u : 0u) << 25);
            __builtin_nontemporal_store(word, &packed_out[pix]);
        } else {
            uint8_t o = (D == 0) ? (uint8_t)255 : (uint8_t)umin_(15u, (D - 1u) / 3u);
            bucket_out[pix] = o;
        }
    }
}

// ---------------- Kernel 3: bilinear sampling + fusion ----------------
static __device__ __forceinline__ float decode_w8(uint32_t k) {  // u8 bucket
    if (k == 255u) return 0.0f;
    float v = 0.1f + (float)k * 0.06f;
    return v < 1.0f ? v : 1.0f;
}
static __device__ __forceinline__ float decode_w5(uint32_t p) {  // packed bucket
    uint32_t k = (p >> 20) & 31u;
    if (k == 31u) return 0.0f;
    float v = 0.1f + (float)k * 0.06f;
    return v < 1.0f ? v : 1.0f;
}

// Packed path: 4 points/thread -> 16 independent gathers in flight, dwordx4 streams.
__global__ __launch_bounds__(256) void sample4_kernel(
    const uint32_t* __restrict__ pimg, const float* __restrict__ xy,
    const float* __restrict__ z, const float* __restrict__ occ_body,
    const float* __restrict__ occ_face, float* __restrict__ out) {
    // XCD-affinity: batch = blockIdx%4 -> under round-robin block->XCD dispatch,
    // each XCD gathers from one 4 MB image = its own L2.
    const int b = blockIdx.x & 3;
    const int n0 = (blockIdx.x >> 2) * 1024 + threadIdx.x * 4;
    const size_t pb = (size_t)b * NPTS;

    f32x4 xv  = __builtin_nontemporal_load((const f32x4*)&xy[pb * 2 + n0]);
    f32x4 yv  = __builtin_nontemporal_load((const f32x4*)&xy[pb * 2 + NPTS + n0]);
    f32x4 zv  = __builtin_nontemporal_load((const f32x4*)&z[pb + n0]);
    f32x4 obv = __builtin_nontemporal_load((const f32x4*)&occ_body[pb + n0]);
    f32x4 ofv = __builtin_nontemporal_load((const f32x4*)&occ_face[pb + n0]);

    const uint32_t* img = pimg + (size_t)b * HWIMG;
    f32x4 res;
    size_t idx[4][4];
    float wgt[4][4];
#pragma unroll
    for (int j = 0; j < 4; ++j) {
        float fx = ((xv[j] + 1.0f) * 0.5f) * 1023.0f;
        float fy = ((yv[j] + 1.0f) * 0.5f) * 1023.0f;
        float x0f = floorf(fx), y0f = floorf(fy);
        float wx = fx - x0f, wy = fy - y0f;
        int x0i = (int)x0f; x0i = x0i < 0 ? 0 : (x0i > 1023 ? 1023 : x0i);
        int y0i = (int)y0f; y0i = y0i < 0 ? 0 : (y0i > 1023 ? 1023 : y0i);
        int x1i = x0i + 1 > 1023 ? 1023 : x0i + 1;
        int y1i = y0i + 1 > 1023 ? 1023 : y0i + 1;
        idx[j][0] = (size_t)y0i * WW + x0i;
        idx[j][1] = (size_t)y0i * WW + x1i;
        idx[j][2] = (size_t)y1i * WW + x0i;
        idx[j][3] = (size_t)y1i * WW + x1i;
        wgt[j][0] = (1.0f - wx) * (1.0f - wy);
        wgt[j][1] = wx * (1.0f - wy);
        wgt[j][2] = (1.0f - wx) * wy;
        wgt[j][3] = wx * wy;
    }
    uint32_t pw[4][4];
#pragma unroll
    for (int j = 0; j < 4; ++j)        // all 16 gathers issued back-to-back (MLP)
#pragma unroll
        for (int k = 0; k < 4; ++k) pw[j][k] = img[idx[j][k]];

#pragma unroll
    for (int j = 0; j < 4; ++j) {
        float e = (float)((pw[j][0] >> 25) & 1u) * wgt[j][0]
                + (float)((pw[j][1] >> 25) & 1u) * wgt[j][1]
                + (float)((pw[j][2] >> 25) & 1u) * wgt[j][2]
                + (float)((pw[j][3] >> 25) & 1u) * wgt[j][3];
        float w = 0.0f;
        if (e > 0.01f) {
            const float DQS = 1.0f / 1048575.0f;
            float dq = ((float)(pw[j][0] & 0xFFFFFu) * wgt[j][0]
                      + (float)(pw[j][1] & 0xFFFFFu) * wgt[j][1]
                      + (float)(pw[j][2] & 0xFFFFFu) * wgt[j][2]
                      + (float)(pw[j][3] & 0xFFFFFu) * wgt[j][3]) * DQS;
            float la = decode_w5(pw[j][0]) * wgt[j][0] + decode_w5(pw[j][1]) * wgt[j][1]
                     + decode_w5(pw[j][2]) * wgt[j][2] + decode_w5(pw[j][3]) * wgt[j][3];
            float ps = zv[j] - dq;
            w = expf(-(ps * ps) * 1000.0f) * la;
        }
        res[j] = w * ofv[j] + (1.0f - w) * obv[j];
    }
    __builtin_nontemporal_store(res, (f32x4*)&out[pb + n0]);
}

// Fallback (small ws): original scalar 3-image sampling.
__global__ __launch_bounds__(256) void sample_fallback_kernel(
    const float* __restrict__ edge_img, const float* __restrict__ depth_img,
    const uint8_t* __restrict__ wimg,
    const float* __restrict__ xy, const float* __restrict__ z,
    const float* __restrict__ occ_body, const float* __restrict__ occ_face,
    float* __restrict__ out) {
    const int b = blockIdx.x & 3;
    const int n = (blockIdx.x >> 2) * 256 + threadIdx.x;

    float x = xy[(size_t)b * 2 * NPTS + n];
    float y = xy[(size_t)b * 2 * NPTS + NPTS + n];
    float fx = ((x + 1.0f) * 0.5f) * 1023.0f;
    float fy = ((y + 1.0f) * 0.5f) * 1023.0f;
    float x0f = floorf(fx), y0f = floorf(fy);
    float wx = fx - x0f, wy = fy - y0f;
    int x0i = (int)x0f; x0i = x0i < 0 ? 0 : (x0i > 1023 ? 1023 : x0i);
    int y0i = (int)y0f; y0i = y0i < 0 ? 0 : (y0i > 1023 ? 1023 : y0i);
    int x1i = x0i + 1 > 1023 ? 1023 : x0i + 1;
    int y1i = y0i + 1 > 1023 ? 1023 : y0i + 1;

    const size_t base = (size_t)b * HWIMG;
    const size_t i00 = base + (size_t)y0i * WW + x0i;
    const size_t i01 = base + (size_t)y0i * WW + x1i;
    const size_t i10 = base + (size_t)y1i * WW + x0i;
    const size_t i11 = base + (size_t)y1i * WW + x1i;

    const float w00 = (1.0f - wx) * (1.0f - wy);
    const float w01 = wx * (1.0f - wy);
    const float w10 = (1.0f - wx) * wy;
    const float w11 = wx * wy;

    float zv = z[(size_t)b * NPTS + n];
    float ob = occ_body[(size_t)b * NPTS + n];
    float of = occ_face[(size_t)b * NPTS + n];

    float w = 0.0f;
    float e = edge_img[i00] * w00 + edge_img[i01] * w01
            + edge_img[i10] * w10 + edge_img[i11] * w11;
    if (e > 0.01f) {
        float dq = depth_img[i00] * w00 + depth_img[i01] * w01
                 + depth_img[i10] * w10 + depth_img[i11] * w11;
        float la = decode_w8(wimg[i00]) * w00 + decode_w8(wimg[i01]) * w01
                 + decode_w8(wimg[i10]) * w10 + decode_w8(wimg[i11]) * w11;
        float ps = zv - dq;
        w = expf(-(ps * ps) * 1000.0f) * la;
    }
    out[(size_t)b * NPTS + n] = w * of + (1.0f - w) * ob;
}

extern "C" void kernel_launch(void* const* d_in, const int* in_sizes, int n_in,
                              void* d_out, int out_size, void* d_ws, size_t ws_size,
                              hipStream_t stream) {
    const float* mask      = (const float*)d_in[0];
    const float* depth     = (const float*)d_in[1];
    const float* edge      = (const float*)d_in[2];
    const float* xy        = (const float*)d_in[3];
    const float* z         = (const float*)d_in[4];
    const float* occ_body  = (const float*)d_in[5];
    const float* occ_face  = (const float*)d_in[6];
    float* out = (float*)d_out;

    uint8_t* rbuf = (uint8_t*)d_ws;                          // 4 MB
    const size_t need_packed = (size_t)4 * HWIMG + (size_t)4 * HWIMG * 4;  // 20 MB

    row_dt_kernel<<<1024, 256, 0, stream>>>(mask, rbuf);

    if (ws_size >= need_packed) {
        uint32_t* pimg = (uint32_t*)(rbuf + (size_t)4 * HWIMG);  // 16 MB
        col_dt_kernel<true><<<1024, 256, 0, stream>>>(rbuf, edge, depth, nullptr, pimg);
        sample4_kernel<<<1024, 256, 0, stream>>>(pimg, xy, z, occ_body, occ_face, out);
    } else {
        uint8_t* wbuf = rbuf + (size_t)4 * HWIMG;            // 4 MB
        col_dt_kernel<false><<<1024, 256, 0, stream>>>(rbuf, edge, depth, wbuf, nullptr);
        sample_fallback_kernel<<<4096, 256, 0, stream>>>(edge, depth, wbuf,
                                                         xy, z, occ_body, occ_face, out);
    }
}